// Round 3
// baseline (128.352 us; speedup 1.0000x reference)
//
#include <hip/hip_runtime.h>
#include <math.h>

#define H_IMG 256
#define W_IMG 512
#define FS    14
#define L     196
#define DM    384
#define HID   96

// One block per (image, half). half 0 -> pooled rows 0..7, tokens rows 0..6.
//                               half 1 -> pooled rows 6..13, tokens rows 7..13.
__global__ __launch_bounds__(512) void fused_all_kernel(
    const float* __restrict__ img, const float* __restrict__ pos,
    const float* __restrict__ gf,  const float* __restrict__ Wp,
    const float* __restrict__ bp,  const float* __restrict__ w1,
    const float* __restrict__ b1,  const float* __restrict__ w2,
    const float* __restrict__ b2,  float* __restrict__ out, int B)
{
    __shared__ float  sPool[3][8][FS];   // pooled rows rbase..rbase+7
    __shared__ float  sA[3 * HID];       // Wp @ w1
    __shared__ float  sB0[HID];          // bp @ w1 + b1
    __shared__ float  sw2v[HID];
    __shared__ float4 sWp4[3 * DM / 4];  // 288
    __shared__ float4 sbp4[DM / 4];      // 96
    __shared__ float  sMeta[98][5];      // fw, wsum, ps0, ps1, ps2

    const int HW = H_IMG * W_IMG;
    const int tid  = threadIdx.x;
    const int blk  = blockIdx.x;
    const int b    = blk >> 1;
    const int half = blk & 1;
    const int rbase = 6 * half;          // first pooled row held in LDS

    // ---- stage small weights (one load per thread) ----
    if (tid < 288)       sWp4[tid]        = ((const float4*)Wp)[tid];
    else if (tid < 384)  sbp4[tid - 288]  = ((const float4*)bp)[tid - 288];
    else if (tid < 480)  sw2v[tid - 384]  = w2[tid - 384];
    float b2v = b2[0];

    // ---- reference x_start / y_start ----
    float px = fminf(fmaxf(pos[2 * b + 0], 0.f), 1.f);
    float py = fminf(fmaxf(pos[2 * b + 1], 0.f), 1.f);
    int xs = ((int)truncf(px * 512.f - 112.f)) % 512; if (xs < 0) xs += 512;
    float yv = fminf(fmaxf(py * 256.f - 112.f, 0.f), 32.f);
    int ys = (int)floorf(yv);

    if (tid < 448) {
        // ---- phase A: pool 8 rows (2 rows per pass x 4 passes) ----
        int ct   = tid % 224;            // patch column index
        int ihalf = tid / 224;           // which of the 2 rows this pass
        int col = xs + ct; if (col >= W_IMG) col -= W_IMG;   // wraparound
        const float* ipb = img + (size_t)b * 3 * HW + col;
        #pragma unroll
        for (int ii = 0; ii < 4; ++ii) {
            int il = ii * 2 + ihalf;                 // local pooled row 0..7
            int row0 = ys + (rbase + il) * 16;
            const float* ip = ipb + (size_t)row0 * W_IMG;
            float a0 = 0.f, a1 = 0.f, a2 = 0.f;
            #pragma unroll
            for (int dy = 0; dy < 16; ++dy) {
                const float* r = ip + dy * W_IMG;
                a0 += r[0];
                a1 += r[HW];
                a2 += r[2 * HW];
            }
            #pragma unroll
            for (int d = 1; d < 16; d <<= 1) {
                a0 += __shfl_xor(a0, d);
                a1 += __shfl_xor(a1, d);
                a2 += __shfl_xor(a2, d);
            }
            if ((tid & 15) == 0) {
                int pc = ct >> 4;
                sPool[0][il][pc] = a0 * (1.f / 256.f);
                sPool[1][il][pc] = a1 * (1.f / 256.f);
                sPool[2][il][pc] = a2 * (1.f / 256.f);
            }
        }
    } else {
        // ---- phase A': fold MLP layer-1 through the rank-3 projection ----
        int k = tid - 448;                // 0..63 ; also handles k+64 if k<32
        float a0 = 0.f, a1 = 0.f, a2 = 0.f, ab = 0.f;
        float c0 = 0.f, c1 = 0.f, c2 = 0.f, cb = 0.f;
        #pragma unroll 4
        for (int d = 0; d < DM; ++d) {
            float wv  = w1[d * HID + k];
            float w0r = Wp[d], w1r = Wp[DM + d], w2r = Wp[2 * DM + d], bpr = bp[d];
            a0 += w0r * wv; a1 += w1r * wv; a2 += w2r * wv; ab += bpr * wv;
            if (k < 32) {
                float wv2 = w1[d * HID + k + 64];
                c0 += w0r * wv2; c1 += w1r * wv2; c2 += w2r * wv2; cb += bpr * wv2;
            }
        }
        sA[k] = a0; sA[HID + k] = a1; sA[2 * HID + k] = a2; sB0[k] = ab + b1[k];
        if (k < 32) {
            sA[k + 64] = c0; sA[HID + k + 64] = c1; sA[2 * HID + k + 64] = c2;
            sB0[k + 64] = cb + b1[k + 64];
        }
    }
    __syncthreads();

    // ---- phase B: per-token fusion weight + bilinear combos (4 lanes/token) ----
    if (tid < 392) {
        int g = tid >> 2, s = tid & 3;           // token 0..97, sub-lane 0..3
        int il = g / FS, j = g - il * FS;        // il 0..6
        int i  = half * 7 + il;                  // global pooled row of the token
        int lrow = il + half;                    // i - rbase
        float p0 = sPool[0][lrow][j];
        float p1 = sPool[1][lrow][j];
        float p2 = sPool[2][lrow][j];

        float acc = 0.f;
        #pragma unroll
        for (int m = 0; m < 24; ++m) {
            int k = s + 4 * m;
            float x = sB0[k] + p0 * sA[k] + p1 * sA[HID + k] + p2 * sA[2 * HID + k];
            float e = __expf(1.5957691216057308f * (x + 0.044715f * x * x * x));
            float th = 1.f - 2.f / (e + 1.f);    // tanh, saturates cleanly
            acc += 0.5f * x * (1.f + th) * sw2v[k];
        }
        acc += __shfl_xor(acc, 1);
        acc += __shfl_xor(acc, 2);

        if (s == 0) {
            float fw = 1.f / (1.f + __expf(-(acc + b2v)));

            float uj = ((j + 0.5f) * 2.f) / 14.f - 1.f;
            float ui = ((i + 0.5f) * 2.f) / 14.f - 1.f;
            float gx = (224.f / 512.f) * uj + ((2.f * (float)xs + 224.f) / 512.f - 1.f);
            float gy = (224.f / 256.f) * ui + ((2.f * (float)ys + 224.f) / 256.f - 1.f);
            float ix = (gx + 1.f) * 7.f - 0.5f;
            float iy = (gy + 1.f) * 7.f - 0.5f;
            float x0f = floorf(ix), y0f = floorf(iy);
            float wx1 = ix - x0f, wx0 = 1.f - wx1;
            float wy1 = iy - y0f, wy0 = 1.f - wy1;
            int x0 = (int)x0f, y0 = (int)y0f, x1 = x0 + 1, y1 = y0 + 1;

            float ps0 = 0.f, ps1 = 0.f, ps2 = 0.f, wsum = 0.f;
            const int   cx[4] = { x0, x1, x0, x1 };
            const int   cy[4] = { y0, y0, y1, y1 };
            const float cw[4] = { wy0 * wx0, wy0 * wx1, wy1 * wx0, wy1 * wx1 };
            #pragma unroll
            for (int n = 0; n < 4; ++n) {
                int X = cx[n], Y = cy[n], ly = Y - rbase;
                if (X >= 0 && X < FS && Y >= 0 && Y < FS && ly >= 0 && ly < 8) {
                    float w = cw[n];
                    ps0 += w * sPool[0][ly][X];
                    ps1 += w * sPool[1][ly][X];
                    ps2 += w * sPool[2][ly][X];
                    wsum += w;
                }
            }
            sMeta[g][0] = fw;  sMeta[g][1] = wsum;
            sMeta[g][2] = ps0; sMeta[g][3] = ps1; sMeta[g][4] = ps2;
        }
    }
    __syncthreads();

    // ---- phase C: stream the block's contiguous 98x384 slice of gf ----
    size_t base4 = ((size_t)b * L + (size_t)half * 98) * (DM / 4);
    const float4* gf4  = (const float4*)gf  + base4;
    float4*       out4 = (float4*)out       + base4;
    for (int item = tid; item < 98 * (DM / 4); item += 512) {
        int tl = item / (DM / 4);
        int d4 = item - tl * (DM / 4);
        float fw   = sMeta[tl][0];
        float wsum = sMeta[tl][1];
        float ps0  = sMeta[tl][2];
        float ps1  = sMeta[tl][3];
        float ps2  = sMeta[tl][4];
        float4 g4 = gf4[item];
        float4 W0 = sWp4[d4];
        float4 W1 = sWp4[96 + d4];
        float4 W2 = sWp4[192 + d4];
        float4 BV = sbp4[d4];
        float4 o;
        o.x = g4.x + fw * (wsum * BV.x + ps0 * W0.x + ps1 * W1.x + ps2 * W2.x);
        o.y = g4.y + fw * (wsum * BV.y + ps0 * W0.y + ps1 * W1.y + ps2 * W2.y);
        o.z = g4.z + fw * (wsum * BV.z + ps0 * W0.z + ps1 * W1.z + ps2 * W2.z);
        o.w = g4.w + fw * (wsum * BV.w + ps0 * W0.w + ps1 * W1.w + ps2 * W2.w);
        out4[item] = o;
    }
}

extern "C" void kernel_launch(void* const* d_in, const int* in_sizes, int n_in,
                              void* d_out, int out_size, void* d_ws, size_t ws_size,
                              hipStream_t stream) {
    const float* images    = (const float*)d_in[0];
    const float* positions = (const float*)d_in[1];
    const float* gf        = (const float*)d_in[2];
    const float* Wp        = (const float*)d_in[3];
    const float* bp        = (const float*)d_in[4];
    const float* w1        = (const float*)d_in[5];
    const float* b1        = (const float*)d_in[6];
    const float* w2        = (const float*)d_in[7];
    const float* b2        = (const float*)d_in[8];

    const int B = in_sizes[1] / 2;   // positions is (B,2)

    hipLaunchKernelGGL(fused_all_kernel, dim3(2 * B), dim3(512), 0, stream,
                       images, positions, gf, Wp, bp, w1, b1, w2, b2,
                       (float*)d_out, B);
}